// Round 1
// baseline (1063.519 us; speedup 1.0000x reference)
//
#include <hip/hip_runtime.h>
#include <math.h>

#define PI_D 3.14159265358979323846

// ---------------- workspace layout (float offsets) ----------------
#define OFF_SCAL   0u                 // 4 floats: a0,a1,b0(beta0),b1(beta1)
#define OFF_W0T    4u                 // 289*128
#define OFF_W1T    36996u             // 1089*128
#define OFF_W2T    176388u            // 2*128*128 [i][k][o']
#define OFF_TW17   209156u            // 8*289*128  [r][ky][kx][o]
#define OFF_TW33   505092u            // 8*1089*128 [r][ky][kx][o]
#define OFF_XOUT   1620228u           // 8*8*2304*128 [b][r][pix][o]
#define OFF_A0     20494596u          // 8*4*2304
#define OFF_A1     20568324u          // 8*8*2304
#define OFF_Z0     20715780u          // 8*4*4*2304
#define OFF_Z1     21010692u          // 8*4*8*2304
// total 21600516 floats = 86.4 MB

__device__ __forceinline__ float off_r(int r) {
  int m = (r <= 4) ? r : r - 8;       // 0,1,2,3,4,-3,-2,-1 (x pi/4)
  return (float)(PI_D / 4.0) * (float)m;
}
__device__ __forceinline__ float lrelu_f(float v) { return (v >= 0.f) ? v : 0.01f * v; }

// ---------------- scalars: alphas / betas ----------------
__global__ void k_scalars(const float* kw, const float* gk, const float* rw,
                          const float* gr, float* scal) {
  if (threadIdx.x == 0 && blockIdx.x == 0) {
    float a0 = (kw[0] + gk[0]) * 0.1f, a1 = (kw[1] + gk[1]) * 0.1f;
    float m = fmaxf(a0, a1);
    float e0 = expf(a0 - m), e1 = expf(a1 - m), inv = 1.f / (e0 + e1);
    scal[0] = e0 * inv; scal[1] = e1 * inv;
    float b0 = (rw[0] + gr[0]) * 0.1f, b1 = (rw[1] + gr[1]) * 0.1f;
    m = fmaxf(b0, b1);
    e0 = expf(b0 - m); e1 = expf(b1 - m); inv = 1.f / (e0 + e1);
    scal[2] = e0 * inv; scal[3] = e1 * inv;
  }
}

// ---------------- transposes: w -> [pos][o], w2 -> [i][k][o'] ----------------
__global__ void k_transpose(const float* __restrict__ w0, const float* __restrict__ w1,
                            const float* __restrict__ w2, float* __restrict__ w0T,
                            float* __restrict__ w1T, float* __restrict__ w2T) {
  int idx = blockIdx.x * blockDim.x + threadIdx.x;
  if (idx < 289 * 128) {
    int o = idx & 127, pos = idx >> 7;
    w0T[pos * 128 + o] = w0[o * 289 + pos];
    return;
  }
  idx -= 289 * 128;
  if (idx < 1089 * 128) {
    int o = idx & 127, pos = idx >> 7;
    w1T[pos * 128 + o] = w1[o * 1089 + pos];
    return;
  }
  idx -= 1089 * 128;
  if (idx < 2 * 128 * 128) {
    int o = idx & 127, t = idx >> 7;
    int k = t & 127, i = t >> 7;
    w2T[(i * 128 + k) * 128 + o] = w2[(i * 128 + o) * 128 + k];
  }
}

// ---------------- kernel rotation (grid_sample bilinear, zero pad) ----------------
__global__ void k_rotate(const float* __restrict__ wT, float* __restrict__ dst,
                         int k, int total) {
  int idx = blockIdx.x * blockDim.x + threadIdx.x;
  if (idx >= total) return;
  int o = idx & 127, t = idx >> 7;
  int j = t % k; t /= k;
  int i = t % k; int r = t / k;
  float theta = (float)(PI_D / 4.0) * (float)r;
  float c = cosf(theta), s = sinf(theta);
  float cy = (2.0f * (float)i + 1.0f) / (float)k - 1.0f;
  float cx = (2.0f * (float)j + 1.0f) / (float)k - 1.0f;
  float sx = c * cx - s * cy;
  float sy = s * cx + c * cy;
  float fx = ((sx + 1.0f) * (float)k - 1.0f) * 0.5f;
  float fy = ((sy + 1.0f) * (float)k - 1.0f) * 0.5f;
  float x0f = floorf(fx), y0f = floorf(fy);
  int x0 = (int)x0f, y0 = (int)y0f;
  float wx1 = fx - x0f, wy1 = fy - y0f;
  float acc = 0.f;
#define CORNER(Y, X, CW) { int yy = (Y), xx = (X); \
    if (yy >= 0 && yy < k && xx >= 0 && xx < k) acc += wT[(yy * k + xx) * 128 + o] * (CW); }
  CORNER(y0,     x0,     (1.f - wy1) * (1.f - wx1));
  CORNER(y0,     x0 + 1, (1.f - wy1) * wx1);
  CORNER(y0 + 1, x0,     wy1 * (1.f - wx1));
  CORNER(y0 + 1, x0 + 1, wy1 * wx1);
#undef CORNER
  dst[idx] = acc;   // layout ((r*k+i)*k+j)*128+o == idx
}

// ---------------- big direct conv: both kernel sizes, fused combine ----------------
// grid 512 = 8b * 8r * 8ct, block 256 = 16 channels * 16 pixel-slots
__global__ __launch_bounds__(256, 2) void k_conv(
    const float* __restrict__ x, const float* __restrict__ tw17,
    const float* __restrict__ tw33, const float* __restrict__ b17,
    const float* __restrict__ b33, const float* __restrict__ scal,
    float* __restrict__ xout) {
  __shared__ __align__(16) float tile[80][80];
  int blk = blockIdx.x;
  int b = blk >> 6;
  int r = (blk >> 3) & 7;
  int ct = blk & 7;
  int tid = threadIdx.x;
  int o = (ct << 4) + (tid & 15);
  int slot = tid >> 4;                 // 0..15
  for (int idx = tid; idx < 6400; idx += 256) {
    int ty = idx / 80, tx = idx - ty * 80;
    float v = 0.f;
    if (ty >= 8 && ty < 72 && tx >= 8 && tx < 72) v = x[(b * 64 + ty - 8) * 64 + tx - 8];
    tile[ty][tx] = v;
  }
  __syncthreads();
  float a0 = scal[0], a1 = scal[1];
  float bias17 = b17[o], bias33 = b33[o];
  const float* w33base = tw33 + (size_t)r * (33 * 33 * 128) + o;
  const float* w17base = tw17 + (size_t)r * (17 * 17 * 128) + o;
  for (int i = 0; i < 18; ++i) {
    int s = slot + (i << 4);           // 0..287
    int y = s / 6;
    int x0 = (s - y * 6) << 3;
    float acc33[8] = {0, 0, 0, 0, 0, 0, 0, 0};
    float acc17[8] = {0, 0, 0, 0, 0, 0, 0, 0};
#pragma unroll 1
    for (int ky = 0; ky < 33; ++ky) {
      float xin[40];
      const float4* rowp = (const float4*)(&tile[y + ky][x0]);
#pragma unroll
      for (int q = 0; q < 10; ++q) {
        float4 v4 = rowp[q];
        xin[4 * q] = v4.x; xin[4 * q + 1] = v4.y;
        xin[4 * q + 2] = v4.z; xin[4 * q + 3] = v4.w;
      }
      const float* w33row = w33base + ky * (33 * 128);
#pragma unroll
      for (int kx = 0; kx < 33; ++kx) {
        float w = w33row[kx << 7];
#pragma unroll
        for (int p = 0; p < 8; ++p) acc33[p] = fmaf(w, xin[kx + p], acc33[p]);
      }
      if (ky >= 8 && ky < 25) {
        const float* w17row = w17base + (ky - 8) * (17 * 128);
#pragma unroll
        for (int kx = 0; kx < 17; ++kx) {
          float w = w17row[kx << 7];
#pragma unroll
          for (int p = 0; p < 8; ++p) acc17[p] = fmaf(w, xin[kx + 8 + p], acc17[p]);
        }
      }
    }
    size_t obase = (((size_t)b * 8 + r) * 2304 + (y * 48 + x0)) * 128 + o;
#pragma unroll
    for (int p = 0; p < 8; ++p) {
      float v17 = lrelu_f(acc17[p] + bias17);
      float v33 = lrelu_f(acc33[p] + bias33);
      xout[obase + ((size_t)p << 7)] = a0 * v17 + a1 * v33;
    }
  }
}

// ---------------- fused 1x1 conv (h) + attn/z heads ----------------
// grid = 8 * nR * 36, block 256: 64 pixels x 128 o', thread = 4 o' x 8 px
__global__ __launch_bounds__(256, 2) void k_pw(
    const float* __restrict__ xout, const float* __restrict__ w2T,
    const float* __restrict__ b2, const float* __restrict__ wa,
    const float* __restrict__ ba, const float* __restrict__ wz,
    const float* __restrict__ bz, int nR, int rstep,
    float* __restrict__ attn_out, float* __restrict__ z_out) {
  __shared__ float hs[64 * 133];
  int blk = blockIdx.x;
  int pblk = blk % 36;
  int t = blk / 36;
  int rl = t % nR;
  int b = t / nR;
  int pix0 = pblk * 64;
  int tid = threadIdx.x;
  int og = tid & 31, pg = tid >> 5;
  const float* xrow = xout + (((size_t)b * 8 + (size_t)rl * rstep) * 2304 + pix0 + pg * 8) * 128;
  float acc[4][8];
#pragma unroll
  for (int jj = 0; jj < 4; ++jj)
#pragma unroll
    for (int p = 0; p < 8; ++p) acc[jj][p] = 0.f;
#pragma unroll 1
  for (int kq = 0; kq < 32; ++kq) {
    float4 xv[8];
#pragma unroll
    for (int p = 0; p < 8; ++p) xv[p] = *(const float4*)(xrow + (size_t)p * 128 + kq * 4);
#pragma unroll
    for (int kk = 0; kk < 4; ++kk) {
      float4 wv = *(const float4*)(w2T + (kq * 4 + kk) * 128 + og * 4);
#pragma unroll
      for (int p = 0; p < 8; ++p) {
        float xval = (kk == 0) ? xv[p].x : (kk == 1) ? xv[p].y : (kk == 2) ? xv[p].z : xv[p].w;
        acc[0][p] = fmaf(wv.x, xval, acc[0][p]);
        acc[1][p] = fmaf(wv.y, xval, acc[1][p]);
        acc[2][p] = fmaf(wv.z, xval, acc[2][p]);
        acc[3][p] = fmaf(wv.w, xval, acc[3][p]);
      }
    }
  }
#pragma unroll
  for (int jj = 0; jj < 4; ++jj) {
    float bb = b2[og * 4 + jj];
#pragma unroll
    for (int p = 0; p < 8; ++p)
      hs[(pg * 8 + p) * 133 + og * 4 + jj] = lrelu_f(acc[jj][p] + bb);
  }
  __syncthreads();
  int j = tid >> 6;
  int px = tid & 63;
  float accz = bz[j];
  float acca = (j == 0) ? ba[0] : 0.f;
  const float* wzr = wz + j * 128;
#pragma unroll 1
  for (int k = 0; k < 128; ++k) {
    float hv = hs[px * 133 + k];
    accz = fmaf(wzr[k], hv, accz);
    if (j == 0) acca = fmaf(wa[k], hv, acca);
  }
  z_out[(((size_t)b * 4 + j) * nR + rl) * 2304 + pix0 + px] = accz;
  if (j == 0) attn_out[((size_t)b * nR + rl) * 2304 + pix0 + px] = acca;
}

// ---------------- attn scatter + p_r; also p_r / offsets outputs ----------------
__global__ void k_attn_combine(const float* __restrict__ a0buf, const float* __restrict__ a1buf,
                               const float* __restrict__ scal, float* __restrict__ out0,
                               float* __restrict__ out2, float* __restrict__ out4) {
  int idx = blockIdx.x * blockDim.x + threadIdx.x;
  if (idx < 8) {
    float off = off_r(idx);
    out4[idx] = off;
    float q = off / (float)PI_D;
    out2[idx] = -0.5f * q * q - logf((float)PI_D) - 0.5f * logf(2.0f * (float)PI_D);
  }
  if (idx >= 147456) return;
  int pix = idx % 2304;
  int t = idx / 2304;
  int r = t & 7, b = t >> 3;
  float v = scal[3] * a1buf[idx];
  if (!(r & 1)) v += scal[2] * a0buf[((size_t)b * 4 + (r >> 1)) * 2304 + pix];
  float q = off_r(r) / (float)PI_D;
  v += -0.5f * q * q - logf((float)PI_D) - 0.5f * logf(2.0f * (float)PI_D);
  out0[idx] = v;
}

// ---------------- per-batch softmax / log_softmax over 18432 ----------------
__global__ __launch_bounds__(1024) void k_softmax(const float* __restrict__ out0,
                                                  const float* __restrict__ g,
                                                  float* __restrict__ out1,
                                                  float* __restrict__ out3) {
  int b = blockIdx.x;
  int tid = threadIdx.x;
  const float* v = out0 + (size_t)b * 18432;
  const float* gb = g + (size_t)b * 18432;
  float vl[18], gl[18];
  float m1 = -1e30f, m2 = -1e30f;
#pragma unroll
  for (int t = 0; t < 18; ++t) {
    float vv = v[tid + (t << 10)];
    float gg = gb[tid + (t << 10)];
    vl[t] = vv;
    gl[t] = vv + gg;
    m1 = fmaxf(m1, vv);
    m2 = fmaxf(m2, gl[t]);
  }
  __shared__ float red[32];
  for (int off = 32; off > 0; off >>= 1) {
    m1 = fmaxf(m1, __shfl_xor(m1, off));
    m2 = fmaxf(m2, __shfl_xor(m2, off));
  }
  int wid = tid >> 6, lane = tid & 63;
  if (lane == 0) { red[wid] = m1; red[wid + 16] = m2; }
  __syncthreads();
  float M1 = red[0], M2 = red[16];
#pragma unroll
  for (int w = 1; w < 16; ++w) { M1 = fmaxf(M1, red[w]); M2 = fmaxf(M2, red[w + 16]); }
  __syncthreads();
  float s1 = 0.f, s2 = 0.f;
#pragma unroll
  for (int t = 0; t < 18; ++t) { s1 += expf(vl[t] - M1); s2 += expf(gl[t] - M2); }
  for (int off = 32; off > 0; off >>= 1) {
    s1 += __shfl_xor(s1, off);
    s2 += __shfl_xor(s2, off);
  }
  if (lane == 0) { red[wid] = s1; red[wid + 16] = s2; }
  __syncthreads();
  float S1 = 0.f, S2 = 0.f;
#pragma unroll
  for (int w = 0; w < 16; ++w) { S1 += red[w]; S2 += red[w + 16]; }
  float lse = M1 + logf(S1);
  float inv2 = 1.0f / S2;
  float* o1 = out1 + (size_t)b * 18432;
  float* o3 = out3 + (size_t)b * 18432;
#pragma unroll
  for (int t = 0; t < 18; ++t) {
    o1[tid + (t << 10)] = vl[t] - lse;
    o3[tid + (t << 10)] = expf(gl[t] - M2) * inv2;
  }
}

// ---------------- z scatter + theta ----------------
__global__ void k_ztheta(const float* __restrict__ z0buf, const float* __restrict__ z1buf,
                         const float* __restrict__ scal, float* __restrict__ out5,
                         float* __restrict__ out6) {
  int idx = blockIdx.x * blockDim.x + threadIdx.x;
  if (idx >= 589824) return;
  int pix = idx % 2304;
  int t = idx / 2304;
  int r = t & 7;
  t >>= 3;
  int c = t & 3;
  int b = t >> 2;
  float v = scal[3] * z1buf[idx];
  if (!(r & 1)) v += scal[2] * z0buf[(((size_t)b * 4 + c) * 4 + (r >> 1)) * 2304 + pix];
  out6[idx] = v;
  if (c == 0)      out5[(((size_t)b * 2 + 0) * 8 + r) * 2304 + pix] = v + off_r(r);
  else if (c == 1) out5[(((size_t)b * 2 + 1) * 8 + r) * 2304 + pix] = v;
}

// ---------------- launcher ----------------
extern "C" void kernel_launch(void* const* d_in, const int* in_sizes, int n_in,
                              void* d_out, int out_size, void* d_ws, size_t ws_size,
                              hipStream_t stream) {
  const float* x   = (const float*)d_in[0];
  const float* ksz = (const float*)d_in[1];
  const float* rdw = (const float*)d_in[2];
  const float* w0  = (const float*)d_in[3];
  const float* b0  = (const float*)d_in[4];
  const float* w1  = (const float*)d_in[5];
  const float* b1  = (const float*)d_in[6];
  const float* w2  = (const float*)d_in[7];
  const float* b2  = (const float*)d_in[8];
  const float* wa  = (const float*)d_in[9];
  const float* ba  = (const float*)d_in[10];
  const float* wz  = (const float*)d_in[11];
  const float* bz  = (const float*)d_in[12];
  const float* gks = (const float*)d_in[13];
  const float* grd = (const float*)d_in[14];
  const float* gat = (const float*)d_in[15];
  float* out = (float*)d_out;
  float* ws  = (float*)d_ws;

  float* scal = ws + OFF_SCAL;
  float* w0T  = ws + OFF_W0T;
  float* w1T  = ws + OFF_W1T;
  float* w2T  = ws + OFF_W2T;
  float* tw17 = ws + OFF_TW17;
  float* tw33 = ws + OFF_TW33;
  float* xout = ws + OFF_XOUT;
  float* a0b  = ws + OFF_A0;
  float* a1b  = ws + OFF_A1;
  float* z0b  = ws + OFF_Z0;
  float* z1b  = ws + OFF_Z1;

  float* out0 = out;
  float* out1 = out + 147456;
  float* out2 = out + 294912;
  float* out3 = out + 294920;
  float* out4 = out + 442376;
  float* out5 = out + 442384;
  float* out6 = out + 737296;

  k_scalars<<<1, 64, 0, stream>>>(ksz, gks, rdw, grd, scal);
  k_transpose<<<817, 256, 0, stream>>>(w0, w1, w2, w0T, w1T, w2T);
  k_rotate<<<1156, 256, 0, stream>>>(w0T, tw17, 17, 8 * 17 * 17 * 128);
  k_rotate<<<4356, 256, 0, stream>>>(w1T, tw33, 33, 8 * 33 * 33 * 128);
  k_conv<<<512, 256, 0, stream>>>(x, tw17, tw33, b0, b1, scal, xout);
  // i = 0: r-dim 4 (stride 2)
  k_pw<<<8 * 4 * 36, 256, 0, stream>>>(xout, w2T, b2, wa, ba, wz, bz,
                                       4, 2, a0b, z0b);
  // i = 1: r-dim 8 (stride 1)
  k_pw<<<8 * 8 * 36, 256, 0, stream>>>(xout, w2T + 128 * 128, b2 + 128, wa + 128,
                                       ba + 1, wz + 4 * 128, bz + 4,
                                       8, 1, a1b, z1b);
  k_attn_combine<<<576, 256, 0, stream>>>(a0b, a1b, scal, out0, out2, out4);
  k_softmax<<<8, 1024, 0, stream>>>(out0, gat, out1, out3);
  k_ztheta<<<2304, 256, 0, stream>>>(z0b, z1b, scal, out5, out6);
}

// Round 3
// 426.450 us; speedup vs baseline: 2.4939x; 2.4939x over previous
//
#include <hip/hip_runtime.h>
#include <hip/hip_bf16.h>
#include <math.h>

#define PI_D 3.14159265358979323846

typedef __attribute__((ext_vector_type(8))) short bf16x8;
typedef __attribute__((ext_vector_type(4))) float f32x4;

// ---------------- workspace layout (float offsets) ----------------
#define OFF_SCAL   0u                 // 4 floats
#define OFF_W0T    4u                 // 289*128
#define OFF_W1T    36996u             // 1089*128
#define OFF_W2T    176388u            // 2*128*128 [i][k][o']
#define OFF_BF     209156u            // Bfrag: 8r*55c*4kb*128o*8j bf16 = 901120 floats
#define OFF_XOUT   1110276u           // 8*8*2304*128 f32
#define OFF_A0     19984644u          // 8*4*2304
#define OFF_A1     20058372u          // 8*8*2304
#define OFF_Z0     20205828u          // 8*4*4*2304
#define OFF_Z1     20500740u          // 8*4*8*2304  -> ends 21090564 floats = 84.4 MB

#define NS33 42                       // K-steps for 33-kernel (rows padded to 40 taps)
#define NS17 13                       // K-steps for 17-kernel (rows padded to 24 taps)
#define NSTOT 55

__device__ __forceinline__ float off_r(int r) {
  int m = (r <= 4) ? r : r - 8;
  return (float)(PI_D / 4.0) * (float)m;
}
__device__ __forceinline__ float lrelu_f(float v) { return (v >= 0.f) ? v : 0.01f * v; }
__device__ __forceinline__ short f2bf(float f) {
  __bf16 h = (__bf16)f;
  return __builtin_bit_cast(short, h);
}

// ---------------- scalars: alphas / betas ----------------
__global__ void k_scalars(const float* kw, const float* gk, const float* rw,
                          const float* gr, float* scal) {
  if (threadIdx.x == 0 && blockIdx.x == 0) {
    float a0 = (kw[0] + gk[0]) * 0.1f, a1 = (kw[1] + gk[1]) * 0.1f;
    float m = fmaxf(a0, a1);
    float e0 = expf(a0 - m), e1 = expf(a1 - m), inv = 1.f / (e0 + e1);
    scal[0] = e0 * inv; scal[1] = e1 * inv;
    float b0 = (rw[0] + gr[0]) * 0.1f, b1 = (rw[1] + gr[1]) * 0.1f;
    m = fmaxf(b0, b1);
    e0 = expf(b0 - m); e1 = expf(b1 - m); inv = 1.f / (e0 + e1);
    scal[2] = e0 * inv; scal[3] = e1 * inv;
  }
}

// ---------------- transposes: w -> [pos][o], w2 -> [i][k][o'] ----------------
__global__ void k_transpose(const float* __restrict__ w0, const float* __restrict__ w1,
                            const float* __restrict__ w2, float* __restrict__ w0T,
                            float* __restrict__ w1T, float* __restrict__ w2T) {
  int idx = blockIdx.x * blockDim.x + threadIdx.x;
  if (idx < 289 * 128) {
    int o = idx & 127, pos = idx >> 7;
    w0T[pos * 128 + o] = w0[o * 289 + pos];
    return;
  }
  idx -= 289 * 128;
  if (idx < 1089 * 128) {
    int o = idx & 127, pos = idx >> 7;
    w1T[pos * 128 + o] = w1[o * 1089 + pos];
    return;
  }
  idx -= 1089 * 128;
  if (idx < 2 * 128 * 128) {
    int o = idx & 127, t = idx >> 7;
    int k = t & 127, i = t >> 7;
    w2T[(i * 128 + k) * 128 + o] = w2[(i * 128 + o) * 128 + k];
  }
}

// ---------------- fused rotation + B-fragment prep ----------------
// Bfrag[r][c][kb][o][j] bf16, thread = (r,c,kb,o), writes 8 j's (one short8)
__global__ void k_bprep(const float* __restrict__ w0T, const float* __restrict__ w1T,
                        short* __restrict__ bfrag) {
  int t = blockIdx.x * blockDim.x + threadIdx.x;   // 225280 threads
  int o = t & 127;
  int q = t >> 7;
  int kb = q & 3; q >>= 2;
  int c = q % 55; int r = q / 55;
  float theta = (float)(PI_D / 4.0) * (float)r;
  float cth = cosf(theta), sth = sinf(theta);
  short out[8];
#pragma unroll
  for (int j = 0; j < 8; ++j) {
    float val = 0.f;
    int kk, k, dy, dx;
    const float* wT;
    if (c < NS33) { kk = 32 * c + 8 * kb + j; k = 33; dy = kk / 40; dx = kk - 40 * dy; wT = w1T; }
    else          { kk = 32 * (c - NS33) + 8 * kb + j; k = 17; dy = kk / 24; dx = kk - 24 * dy; wT = w0T; }
    if (dy < k && dx < k) {
      float cy = (2.0f * (float)dy + 1.0f) / (float)k - 1.0f;
      float cx = (2.0f * (float)dx + 1.0f) / (float)k - 1.0f;
      float sx = cth * cx - sth * cy;
      float sy = sth * cx + cth * cy;
      float fx = ((sx + 1.0f) * (float)k - 1.0f) * 0.5f;
      float fy = ((sy + 1.0f) * (float)k - 1.0f) * 0.5f;
      float x0f = floorf(fx), y0f = floorf(fy);
      int x0 = (int)x0f, y0 = (int)y0f;
      float wx1 = fx - x0f, wy1 = fy - y0f;
      float acc = 0.f;
#define CORNER(Y, X, CW) { int yy = (Y), xx = (X); \
      if (yy >= 0 && yy < k && xx >= 0 && xx < k) acc += wT[(yy * k + xx) * 128 + o] * (CW); }
      CORNER(y0,     x0,     (1.f - wy1) * (1.f - wx1));
      CORNER(y0,     x0 + 1, (1.f - wy1) * wx1);
      CORNER(y0 + 1, x0,     wy1 * (1.f - wx1));
      CORNER(y0 + 1, x0 + 1, wy1 * wx1);
#undef CORNER
      val = acc;
    }
    out[j] = f2bf(val);
  }
  *(bf16x8*)(bfrag + (size_t)t * 8) =
      (bf16x8){out[0], out[1], out[2], out[3], out[4], out[5], out[6], out[7]};
}

// ---------------- MFMA implicit-GEMM conv ----------------
// grid 2304 = (8b*8r)*36pt, block 256 = 4 waves (2 wm x 2 wn)
// block tile: M=64 pixels, N=128 outputs; K: 42 steps (k33) + 13 steps (k17)
#define TDW 3080                      // 35 rows x 88 cols (f32 dwords)
__global__ __launch_bounds__(256, 4) void k_conv_mfma(
    const float* __restrict__ x, const short* __restrict__ bfrag,
    const float* __restrict__ b17, const float* __restrict__ b33,
    const float* __restrict__ scal, float* __restrict__ xout) {
  __shared__ float tile[TDW + 2 + TDW];     // tileA [0..3081], tileB at 3082 (shift-by-1 copy)
  float* tB = tile + (TDW + 2);
  int blk = blockIdx.x;
  int pt = blk % 36; int t2 = blk / 36; int r = t2 & 7, b = t2 >> 3;
  int p0 = pt * 64;
  int ybase = p0 / 48;
  int tid = threadIdx.x;
  // ---- stage x tile (bf16 happens at fragment build; tile kept f32) ----
  for (int idx = tid; idx < TDW; idx += 256) {
    int ty = idx / 88, tx = idx - ty * 88;
    int gy = ybase + ty - 8, gx = tx - 8;
    float v = 0.f;
    if (gy >= 0 && gy < 64 && gx >= 0 && gx < 64) v = x[(b * 64 + gy) * 64 + gx];
    tile[idx] = v;
    if (idx > 0) tB[idx - 1] = v;
  }
  if (tid == 0) { tB[TDW - 1] = 0.f; tile[TDW] = 0.f; tile[TDW + 1] = 0.f; }
  __syncthreads();

  int lane = tid & 63, w = tid >> 6;
  int wm = w >> 1, wn = w & 1;
  int kc = lane >> 4;                 // K-chunk of this lane (A & B operands)
  int ln = lane & 15;
  int mloc[2];
#pragma unroll
  for (int mf = 0; mf < 2; ++mf) {
    int p = p0 + wm * 32 + mf * 16 + ln;
    int ym = p / 48, xm = p - ym * 48;
    mloc[mf] = (ym - ybase) * 88 + xm;
  }
  const short* bb = bfrag + (size_t)r * (55 * 4 * 128 * 8);
  int nb0 = wn * 64;

  f32x4 acc33[2][4];
#pragma unroll
  for (int mf = 0; mf < 2; ++mf)
#pragma unroll
    for (int nf = 0; nf < 4; ++nf) acc33[mf][nf] = (f32x4){0.f, 0.f, 0.f, 0.f};

#define LOADB(dst, cg)                                                          \
  {                                                                             \
    _Pragma("unroll")                                                           \
    for (int nf = 0; nf < 4; ++nf)                                              \
      dst[nf] = *(const bf16x8*)(bb + ((size_t)((cg)*4 + kc) * 128 + nb0 + nf * 16 + ln) * 8); \
  }
#define READA(dst, vv)                                                          \
  {                                                                             \
    int s_ = (vv) & 1;                                                          \
    const float2* pp_ = (const float2*)(tile + s_ * (TDW + 2) + ((vv) & ~1));   \
    float2 f0_ = pp_[0], f1_ = pp_[1], f2_ = pp_[2], f3_ = pp_[3];              \
    dst = (bf16x8){f2bf(f0_.x), f2bf(f0_.y), f2bf(f1_.x), f2bf(f1_.y),          \
                   f2bf(f2_.x), f2bf(f2_.y), f2bf(f3_.x), f2bf(f3_.y)};         \
  }

  // ---- phase 1: 33x33 kernel, rows padded to 40 taps, 42 K-steps ----
  {
    int dxb = 8 * kc;
    int off = dxb;
    bf16x8 bc[4], bn[4];
    LOADB(bc, 0);
    for (int c = 0; c < NS33; ++c) {
      if (c + 1 < NS33) LOADB(bn, c + 1);
      bf16x8 a0, a1;
      READA(a0, mloc[0] + off);
      READA(a1, mloc[1] + off);
#pragma unroll
      for (int nf = 0; nf < 4; ++nf) {
        acc33[0][nf] = __builtin_amdgcn_mfma_f32_16x16x32_bf16(a0, bc[nf], acc33[0][nf], 0, 0, 0);
        acc33[1][nf] = __builtin_amdgcn_mfma_f32_16x16x32_bf16(a1, bc[nf], acc33[1][nf], 0, 0, 0);
      }
#pragma unroll
      for (int nf = 0; nf < 4; ++nf) bc[nf] = bn[nf];
      int nd = dxb + 32;
      int wr = (nd >= 40);
      dxb = wr ? nd - 40 : nd;
      off += wr ? 80 : 32;
    }
  }

  // ---- phase 2: 17x17 kernel, rows padded to 24 taps, 13 K-steps ----
  f32x4 acc17[2][4];
#pragma unroll
  for (int mf = 0; mf < 2; ++mf)
#pragma unroll
    for (int nf = 0; nf < 4; ++nf) acc17[mf][nf] = (f32x4){0.f, 0.f, 0.f, 0.f};
  {
    int t8 = 8 * kc;
    int dy0 = t8 / 24;
    int dxb = t8 - 24 * dy0;
    int off = (8 + dy0) * 88 + 8 + dxb;
    for (int c = 0; c < NS17; ++c) {
      bf16x8 bc[4];
      LOADB(bc, NS33 + c);
      bf16x8 a0, a1;
      READA(a0, mloc[0] + off);
      READA(a1, mloc[1] + off);
#pragma unroll
      for (int nf = 0; nf < 4; ++nf) {
        acc17[0][nf] = __builtin_amdgcn_mfma_f32_16x16x32_bf16(a0, bc[nf], acc17[0][nf], 0, 0, 0);
        acc17[1][nf] = __builtin_amdgcn_mfma_f32_16x16x32_bf16(a1, bc[nf], acc17[1][nf], 0, 0, 0);
      }
      int nd = dxb + 8;
      int wr = (nd >= 24);
      dxb = wr ? nd - 24 : nd;
      off += wr ? 160 : 96;
    }
  }
#undef LOADB
#undef READA

  // ---- epilogue: bias, lrelu, alpha-combine, store ----
  float a0s = scal[0], a1s = scal[1];
  int dq = lane >> 4;
#pragma unroll
  for (int nf = 0; nf < 4; ++nf) {
    int n = nb0 + nf * 16 + ln;
    float bb17 = b17[n], bb33 = b33[n];
#pragma unroll
    for (int mf = 0; mf < 2; ++mf) {
#pragma unroll
      for (int i = 0; i < 4; ++i) {
        int m = wm * 32 + mf * 16 + dq * 4 + i;
        float v = a0s * lrelu_f(acc17[mf][nf][i] + bb17)
                + a1s * lrelu_f(acc33[mf][nf][i] + bb33);
        xout[((size_t)(b * 8 + r) * 2304 + p0 + m) * 128 + n] = v;
      }
    }
  }
}

// ---------------- fused 1x1 conv (h) + attn/z heads ----------------
__global__ __launch_bounds__(256, 2) void k_pw(
    const float* __restrict__ xout, const float* __restrict__ w2T,
    const float* __restrict__ b2, const float* __restrict__ wa,
    const float* __restrict__ ba, const float* __restrict__ wz,
    const float* __restrict__ bz, int nR, int rstep,
    float* __restrict__ attn_out, float* __restrict__ z_out) {
  __shared__ float hs[64 * 133];
  int blk = blockIdx.x;
  int pblk = blk % 36;
  int t = blk / 36;
  int rl = t % nR;
  int b = t / nR;
  int pix0 = pblk * 64;
  int tid = threadIdx.x;
  int og = tid & 31, pg = tid >> 5;
  const float* xrow = xout + (((size_t)b * 8 + (size_t)rl * rstep) * 2304 + pix0 + pg * 8) * 128;
  float acc[4][8];
#pragma unroll
  for (int jj = 0; jj < 4; ++jj)
#pragma unroll
    for (int p = 0; p < 8; ++p) acc[jj][p] = 0.f;
#pragma unroll 1
  for (int kq = 0; kq < 32; ++kq) {
    float4 xv[8];
#pragma unroll
    for (int p = 0; p < 8; ++p) xv[p] = *(const float4*)(xrow + (size_t)p * 128 + kq * 4);
#pragma unroll
    for (int kk = 0; kk < 4; ++kk) {
      float4 wv = *(const float4*)(w2T + (kq * 4 + kk) * 128 + og * 4);
#pragma unroll
      for (int p = 0; p < 8; ++p) {
        float xval = (kk == 0) ? xv[p].x : (kk == 1) ? xv[p].y : (kk == 2) ? xv[p].z : xv[p].w;
        acc[0][p] = fmaf(wv.x, xval, acc[0][p]);
        acc[1][p] = fmaf(wv.y, xval, acc[1][p]);
        acc[2][p] = fmaf(wv.z, xval, acc[2][p]);
        acc[3][p] = fmaf(wv.w, xval, acc[3][p]);
      }
    }
  }
#pragma unroll
  for (int jj = 0; jj < 4; ++jj) {
    float bbv = b2[og * 4 + jj];
#pragma unroll
    for (int p = 0; p < 8; ++p)
      hs[(pg * 8 + p) * 133 + og * 4 + jj] = lrelu_f(acc[jj][p] + bbv);
  }
  __syncthreads();
  int j = tid >> 6;
  int px = tid & 63;
  float accz = bz[j];
  float acca = (j == 0) ? ba[0] : 0.f;
  const float* wzr = wz + j * 128;
#pragma unroll 1
  for (int k = 0; k < 128; ++k) {
    float hv = hs[px * 133 + k];
    accz = fmaf(wzr[k], hv, accz);
    if (j == 0) acca = fmaf(wa[k], hv, acca);
  }
  z_out[(((size_t)b * 4 + j) * nR + rl) * 2304 + pix0 + px] = accz;
  if (j == 0) attn_out[((size_t)b * nR + rl) * 2304 + pix0 + px] = acca;
}

// ---------------- attn scatter + p_r; also p_r / offsets outputs ----------------
__global__ void k_attn_combine(const float* __restrict__ a0buf, const float* __restrict__ a1buf,
                               const float* __restrict__ scal, float* __restrict__ out0,
                               float* __restrict__ out2, float* __restrict__ out4) {
  int idx = blockIdx.x * blockDim.x + threadIdx.x;
  if (idx < 8) {
    float off = off_r(idx);
    out4[idx] = off;
    float q = off / (float)PI_D;
    out2[idx] = -0.5f * q * q - logf((float)PI_D) - 0.5f * logf(2.0f * (float)PI_D);
  }
  if (idx >= 147456) return;
  int pix = idx % 2304;
  int t = idx / 2304;
  int r = t & 7, b = t >> 3;
  float v = scal[3] * a1buf[idx];
  if (!(r & 1)) v += scal[2] * a0buf[((size_t)b * 4 + (r >> 1)) * 2304 + pix];
  float q = off_r(r) / (float)PI_D;
  v += -0.5f * q * q - logf((float)PI_D) - 0.5f * logf(2.0f * (float)PI_D);
  out0[idx] = v;
}

// ---------------- per-batch softmax / log_softmax over 18432 ----------------
__global__ __launch_bounds__(1024) void k_softmax(const float* __restrict__ out0,
                                                  const float* __restrict__ g,
                                                  float* __restrict__ out1,
                                                  float* __restrict__ out3) {
  int b = blockIdx.x;
  int tid = threadIdx.x;
  const float* v = out0 + (size_t)b * 18432;
  const float* gb = g + (size_t)b * 18432;
  float vl[18], gl[18];
  float m1 = -1e30f, m2 = -1e30f;
#pragma unroll
  for (int t = 0; t < 18; ++t) {
    float vv = v[tid + (t << 10)];
    float gg = gb[tid + (t << 10)];
    vl[t] = vv;
    gl[t] = vv + gg;
    m1 = fmaxf(m1, vv);
    m2 = fmaxf(m2, gl[t]);
  }
  __shared__ float red[32];
  for (int off = 32; off > 0; off >>= 1) {
    m1 = fmaxf(m1, __shfl_xor(m1, off));
    m2 = fmaxf(m2, __shfl_xor(m2, off));
  }
  int wid = tid >> 6, lane = tid & 63;
  if (lane == 0) { red[wid] = m1; red[wid + 16] = m2; }
  __syncthreads();
  float M1 = red[0], M2 = red[16];
#pragma unroll
  for (int w = 1; w < 16; ++w) { M1 = fmaxf(M1, red[w]); M2 = fmaxf(M2, red[w + 16]); }
  __syncthreads();
  float s1 = 0.f, s2 = 0.f;
#pragma unroll
  for (int t = 0; t < 18; ++t) { s1 += expf(vl[t] - M1); s2 += expf(gl[t] - M2); }
  for (int off = 32; off > 0; off >>= 1) {
    s1 += __shfl_xor(s1, off);
    s2 += __shfl_xor(s2, off);
  }
  if (lane == 0) { red[wid] = s1; red[wid + 16] = s2; }
  __syncthreads();
  float S1 = 0.f, S2 = 0.f;
#pragma unroll
  for (int w = 0; w < 16; ++w) { S1 += red[w]; S2 += red[w + 16]; }
  float lse = M1 + logf(S1);
  float inv2 = 1.0f / S2;
  float* o1 = out1 + (size_t)b * 18432;
  float* o3 = out3 + (size_t)b * 18432;
#pragma unroll
  for (int t = 0; t < 18; ++t) {
    o1[tid + (t << 10)] = vl[t] - lse;
    o3[tid + (t << 10)] = expf(gl[t] - M2) * inv2;
  }
}

// ---------------- z scatter + theta ----------------
__global__ void k_ztheta(const float* __restrict__ z0buf, const float* __restrict__ z1buf,
                         const float* __restrict__ scal, float* __restrict__ out5,
                         float* __restrict__ out6) {
  int idx = blockIdx.x * blockDim.x + threadIdx.x;
  if (idx >= 589824) return;
  int pix = idx % 2304;
  int t = idx / 2304;
  int r = t & 7;
  t >>= 3;
  int c = t & 3;
  int b = t >> 2;
  float v = scal[3] * z1buf[idx];
  if (!(r & 1)) v += scal[2] * z0buf[(((size_t)b * 4 + c) * 4 + (r >> 1)) * 2304 + pix];
  out6[idx] = v;
  if (c == 0)      out5[(((size_t)b * 2 + 0) * 8 + r) * 2304 + pix] = v + off_r(r);
  else if (c == 1) out5[(((size_t)b * 2 + 1) * 8 + r) * 2304 + pix] = v;
}

// ---------------- launcher ----------------
extern "C" void kernel_launch(void* const* d_in, const int* in_sizes, int n_in,
                              void* d_out, int out_size, void* d_ws, size_t ws_size,
                              hipStream_t stream) {
  const float* x   = (const float*)d_in[0];
  const float* ksz = (const float*)d_in[1];
  const float* rdw = (const float*)d_in[2];
  const float* w0  = (const float*)d_in[3];
  const float* b0  = (const float*)d_in[4];
  const float* w1  = (const float*)d_in[5];
  const float* b1  = (const float*)d_in[6];
  const float* w2  = (const float*)d_in[7];
  const float* b2  = (const float*)d_in[8];
  const float* wa  = (const float*)d_in[9];
  const float* ba  = (const float*)d_in[10];
  const float* wz  = (const float*)d_in[11];
  const float* bz  = (const float*)d_in[12];
  const float* gks = (const float*)d_in[13];
  const float* grd = (const float*)d_in[14];
  const float* gat = (const float*)d_in[15];
  float* out = (float*)d_out;
  float* ws  = (float*)d_ws;

  float* scal = ws + OFF_SCAL;
  float* w0T  = ws + OFF_W0T;
  float* w1T  = ws + OFF_W1T;
  float* w2T  = ws + OFF_W2T;
  short* bfr  = (short*)(ws + OFF_BF);
  float* xout = ws + OFF_XOUT;
  float* a0b  = ws + OFF_A0;
  float* a1b  = ws + OFF_A1;
  float* z0b  = ws + OFF_Z0;
  float* z1b  = ws + OFF_Z1;

  float* out0 = out;
  float* out1 = out + 147456;
  float* out2 = out + 294912;
  float* out3 = out + 294920;
  float* out4 = out + 442376;
  float* out5 = out + 442384;
  float* out6 = out + 737296;

  k_scalars<<<1, 64, 0, stream>>>(ksz, gks, rdw, grd, scal);
  k_transpose<<<817, 256, 0, stream>>>(w0, w1, w2, w0T, w1T, w2T);
  k_bprep<<<880, 256, 0, stream>>>(w0T, w1T, bfr);
  k_conv_mfma<<<2304, 256, 0, stream>>>(x, bfr, b0, b1, scal, xout);
  // i = 0: r-dim 4 (stride 2)
  k_pw<<<8 * 4 * 36, 256, 0, stream>>>(xout, w2T, b2, wa, ba, wz, bz,
                                       4, 2, a0b, z0b);
  // i = 1: r-dim 8 (stride 1)
  k_pw<<<8 * 8 * 36, 256, 0, stream>>>(xout, w2T + 128 * 128, b2 + 128, wa + 128,
                                       ba + 1, wz + 4 * 128, bz + 4,
                                       8, 1, a1b, z1b);
  k_attn_combine<<<576, 256, 0, stream>>>(a0b, a1b, scal, out0, out2, out4);
  k_softmax<<<8, 1024, 0, stream>>>(out0, gat, out1, out3);
  k_ztheta<<<2304, 256, 0, stream>>>(z0b, z1b, scal, out5, out6);
}

// Round 4
// 334.177 us; speedup vs baseline: 3.1825x; 1.2761x over previous
//
#include <hip/hip_runtime.h>
#include <hip/hip_bf16.h>
#include <math.h>

#define PI_D 3.14159265358979323846

typedef __attribute__((ext_vector_type(8))) short bf16x8;
typedef __attribute__((ext_vector_type(4))) float f32x4;

// ---------------- workspace layout (float offsets) ----------------
#define OFF_SCAL   0u                 // 4 floats
#define OFF_W0T    4u                 // 289*128
#define OFF_W1T    36996u             // 1089*128
#define OFF_W2B    176388u            // 2*128*128 bf16 = 16384 floats [i][o'][k]
#define OFF_BF     192772u            // Bfrag: 8r*55c*4kb*128o*8j bf16 = 901120 floats
#define OFF_XOUTB  1093892u           // 8*8*2304*128 bf16 = 9437184 floats
#define OFF_A0     10531076u          // 8*4*2304
#define OFF_A1     10604804u          // 8*8*2304
#define OFF_Z0     10752260u          // 8*4*4*2304
#define OFF_Z1     11047172u          // 8*4*8*2304 -> ends 11636996 floats = 46.5 MB

#define NS33 42                       // K-steps for 33-kernel (rows padded to 40 taps)
#define NS17 13                       // K-steps for 17-kernel (rows padded to 24 taps)

__device__ __forceinline__ float off_r(int r) {
  int m = (r <= 4) ? r : r - 8;
  return (float)(PI_D / 4.0) * (float)m;
}
__device__ __forceinline__ float lrelu_f(float v) { return (v >= 0.f) ? v : 0.01f * v; }
__device__ __forceinline__ short f2bf(float f) {
  __bf16 h = (__bf16)f;
  return __builtin_bit_cast(short, h);
}

// ---------------- scalars: alphas / betas ----------------
__global__ void k_scalars(const float* kw, const float* gk, const float* rw,
                          const float* gr, float* scal) {
  if (threadIdx.x == 0 && blockIdx.x == 0) {
    float a0 = (kw[0] + gk[0]) * 0.1f, a1 = (kw[1] + gk[1]) * 0.1f;
    float m = fmaxf(a0, a1);
    float e0 = expf(a0 - m), e1 = expf(a1 - m), inv = 1.f / (e0 + e1);
    scal[0] = e0 * inv; scal[1] = e1 * inv;
    float b0 = (rw[0] + gr[0]) * 0.1f, b1 = (rw[1] + gr[1]) * 0.1f;
    m = fmaxf(b0, b1);
    e0 = expf(b0 - m); e1 = expf(b1 - m); inv = 1.f / (e0 + e1);
    scal[2] = e0 * inv; scal[3] = e1 * inv;
  }
}

// ---------------- transposes: w -> [pos][o]; w2 -> bf16 cast ----------------
__global__ void k_transpose(const float* __restrict__ w0, const float* __restrict__ w1,
                            const float* __restrict__ w2, float* __restrict__ w0T,
                            float* __restrict__ w1T, short* __restrict__ w2b) {
  int idx = blockIdx.x * blockDim.x + threadIdx.x;
  if (idx < 289 * 128) {
    int o = idx & 127, pos = idx >> 7;
    w0T[pos * 128 + o] = w0[o * 289 + pos];
    return;
  }
  idx -= 289 * 128;
  if (idx < 1089 * 128) {
    int o = idx & 127, pos = idx >> 7;
    w1T[pos * 128 + o] = w1[o * 1089 + pos];
    return;
  }
  idx -= 1089 * 128;
  if (idx < 2 * 128 * 128) {
    w2b[idx] = f2bf(w2[idx]);        // [i][o'][k], k contiguous == B-frag order
  }
}

// ---------------- fused rotation + B-fragment prep ----------------
__global__ void k_bprep(const float* __restrict__ w0T, const float* __restrict__ w1T,
                        short* __restrict__ bfrag) {
  int t = blockIdx.x * blockDim.x + threadIdx.x;   // 225280 threads
  int o = t & 127;
  int q = t >> 7;
  int kb = q & 3; q >>= 2;
  int c = q % 55; int r = q / 55;
  float theta = (float)(PI_D / 4.0) * (float)r;
  float cth = cosf(theta), sth = sinf(theta);
  short out[8];
#pragma unroll
  for (int j = 0; j < 8; ++j) {
    float val = 0.f;
    int kk, k, dy, dx;
    const float* wT;
    if (c < NS33) { kk = 32 * c + 8 * kb + j; k = 33; dy = kk / 40; dx = kk - 40 * dy; wT = w1T; }
    else          { kk = 32 * (c - NS33) + 8 * kb + j; k = 17; dy = kk / 24; dx = kk - 24 * dy; wT = w0T; }
    if (dy < k && dx < k) {
      float cy = (2.0f * (float)dy + 1.0f) / (float)k - 1.0f;
      float cx = (2.0f * (float)dx + 1.0f) / (float)k - 1.0f;
      float sx = cth * cx - sth * cy;
      float sy = sth * cx + cth * cy;
      float fx = ((sx + 1.0f) * (float)k - 1.0f) * 0.5f;
      float fy = ((sy + 1.0f) * (float)k - 1.0f) * 0.5f;
      float x0f = floorf(fx), y0f = floorf(fy);
      int x0 = (int)x0f, y0 = (int)y0f;
      float wx1 = fx - x0f, wy1 = fy - y0f;
      float acc = 0.f;
#define CORNER(Y, X, CW) { int yy = (Y), xx = (X); \
      if (yy >= 0 && yy < k && xx >= 0 && xx < k) acc += wT[(yy * k + xx) * 128 + o] * (CW); }
      CORNER(y0,     x0,     (1.f - wy1) * (1.f - wx1));
      CORNER(y0,     x0 + 1, (1.f - wy1) * wx1);
      CORNER(y0 + 1, x0,     wy1 * (1.f - wx1));
      CORNER(y0 + 1, x0 + 1, wy1 * wx1);
#undef CORNER
      val = acc;
    }
    out[j] = f2bf(val);
  }
  *(bf16x8*)(bfrag + (size_t)t * 8) =
      (bf16x8){out[0], out[1], out[2], out[3], out[4], out[5], out[6], out[7]};
}

// ---------------- MFMA implicit-GEMM conv ----------------
#define TDW 3080                      // 35 rows x 88 cols (f32 dwords)
__global__ __launch_bounds__(256, 4) void k_conv_mfma(
    const float* __restrict__ x, const short* __restrict__ bfrag,
    const float* __restrict__ b17, const float* __restrict__ b33,
    const float* __restrict__ scal, short* __restrict__ xoutb) {
  __shared__ float tile[TDW + 2 + TDW];     // tileA, tileB (shift-by-1 copy)
  float* tB = tile + (TDW + 2);
  int blk = blockIdx.x;
  int pt = blk % 36; int t2 = blk / 36; int r = t2 & 7, b = t2 >> 3;
  int p0 = pt * 64;
  int ybase = p0 / 48;
  int tid = threadIdx.x;
  for (int idx = tid; idx < TDW; idx += 256) {
    int ty = idx / 88, tx = idx - ty * 88;
    int gy = ybase + ty - 8, gx = tx - 8;
    float v = 0.f;
    if (gy >= 0 && gy < 64 && gx >= 0 && gx < 64) v = x[(b * 64 + gy) * 64 + gx];
    tile[idx] = v;
    if (idx > 0) tB[idx - 1] = v;
  }
  if (tid == 0) { tB[TDW - 1] = 0.f; tile[TDW] = 0.f; tile[TDW + 1] = 0.f; }
  __syncthreads();

  int lane = tid & 63, w = tid >> 6;
  int wm = w >> 1, wn = w & 1;
  int kc = lane >> 4;
  int ln = lane & 15;
  int mloc[2];
#pragma unroll
  for (int mf = 0; mf < 2; ++mf) {
    int p = p0 + wm * 32 + mf * 16 + ln;
    int ym = p / 48, xm = p - ym * 48;
    mloc[mf] = (ym - ybase) * 88 + xm;
  }
  const short* bb = bfrag + (size_t)r * (55 * 4 * 128 * 8);
  int nb0 = wn * 64;

  f32x4 acc33[2][4];
#pragma unroll
  for (int mf = 0; mf < 2; ++mf)
#pragma unroll
    for (int nf = 0; nf < 4; ++nf) acc33[mf][nf] = (f32x4){0.f, 0.f, 0.f, 0.f};

#define LOADB(dst, cg)                                                          \
  {                                                                             \
    _Pragma("unroll")                                                           \
    for (int nf = 0; nf < 4; ++nf)                                              \
      dst[nf] = *(const bf16x8*)(bb + ((size_t)((cg)*4 + kc) * 128 + nb0 + nf * 16 + ln) * 8); \
  }
#define READA(dst, vv)                                                          \
  {                                                                             \
    int s_ = (vv) & 1;                                                          \
    const float2* pp_ = (const float2*)(tile + s_ * (TDW + 2) + ((vv) & ~1));   \
    float2 f0_ = pp_[0], f1_ = pp_[1], f2_ = pp_[2], f3_ = pp_[3];              \
    dst = (bf16x8){f2bf(f0_.x), f2bf(f0_.y), f2bf(f1_.x), f2bf(f1_.y),          \
                   f2bf(f2_.x), f2bf(f2_.y), f2bf(f3_.x), f2bf(f3_.y)};         \
  }

  // ---- phase 1: 33x33 kernel ----
  {
    int dxb = 8 * kc;
    int off = dxb;
    bf16x8 bc[4], bn[4];
    LOADB(bc, 0);
    for (int c = 0; c < NS33; ++c) {
      if (c + 1 < NS33) LOADB(bn, c + 1);
      bf16x8 a0, a1;
      READA(a0, mloc[0] + off);
      READA(a1, mloc[1] + off);
#pragma unroll
      for (int nf = 0; nf < 4; ++nf) {
        acc33[0][nf] = __builtin_amdgcn_mfma_f32_16x16x32_bf16(a0, bc[nf], acc33[0][nf], 0, 0, 0);
        acc33[1][nf] = __builtin_amdgcn_mfma_f32_16x16x32_bf16(a1, bc[nf], acc33[1][nf], 0, 0, 0);
      }
#pragma unroll
      for (int nf = 0; nf < 4; ++nf) bc[nf] = bn[nf];
      int nd = dxb + 32;
      int wr = (nd >= 40);
      dxb = wr ? nd - 40 : nd;
      off += wr ? 80 : 32;
    }
  }

  // ---- phase 2: 17x17 kernel ----
  f32x4 acc17[2][4];
#pragma unroll
  for (int mf = 0; mf < 2; ++mf)
#pragma unroll
    for (int nf = 0; nf < 4; ++nf) acc17[mf][nf] = (f32x4){0.f, 0.f, 0.f, 0.f};
  {
    int t8 = 8 * kc;
    int dy0 = t8 / 24;
    int dxb = t8 - 24 * dy0;
    int off = (8 + dy0) * 88 + 8 + dxb;
    for (int c = 0; c < NS17; ++c) {
      bf16x8 bc[4];
      LOADB(bc, NS33 + c);
      bf16x8 a0, a1;
      READA(a0, mloc[0] + off);
      READA(a1, mloc[1] + off);
#pragma unroll
      for (int nf = 0; nf < 4; ++nf) {
        acc17[0][nf] = __builtin_amdgcn_mfma_f32_16x16x32_bf16(a0, bc[nf], acc17[0][nf], 0, 0, 0);
        acc17[1][nf] = __builtin_amdgcn_mfma_f32_16x16x32_bf16(a1, bc[nf], acc17[1][nf], 0, 0, 0);
      }
      int nd = dxb + 8;
      int wr = (nd >= 24);
      dxb = wr ? nd - 24 : nd;
      off += wr ? 160 : 96;
    }
  }
#undef LOADB
#undef READA

  // ---- epilogue: bias, lrelu, alpha-combine, bf16 store ----
  float a0s = scal[0], a1s = scal[1];
  int dq = lane >> 4;
#pragma unroll
  for (int nf = 0; nf < 4; ++nf) {
    int n = nb0 + nf * 16 + ln;
    float bb17 = b17[n], bb33 = b33[n];
#pragma unroll
    for (int mf = 0; mf < 2; ++mf) {
#pragma unroll
      for (int i = 0; i < 4; ++i) {
        int m = wm * 32 + mf * 16 + dq * 4 + i;
        float v = a0s * lrelu_f(acc17[mf][nf][i] + bb17)
                + a1s * lrelu_f(acc33[mf][nf][i] + bb33);
        xoutb[((size_t)(b * 8 + r) * 2304 + p0 + m) * 128 + n] = f2bf(v);
      }
    }
  }
}

// ---------------- MFMA 1x1 conv + fused heads (no LDS) ----------------
// grid = 8 * nR * 36, block 256 = 4 waves, each wave: 16 pixels x 128 channels
__global__ __launch_bounds__(256, 8) void k_pw_mfma(
    const short* __restrict__ xoutb, const short* __restrict__ w2b,
    const float* __restrict__ b2, const float* __restrict__ wa,
    const float* __restrict__ ba, const float* __restrict__ wz,
    const float* __restrict__ bz, int nR, int rstep,
    float* __restrict__ attn_out, float* __restrict__ z_out) {
  int blk = blockIdx.x;
  int pblk = blk % 36;
  int t = blk / 36;
  int rl = t % nR;
  int b = t / nR;
  int tid = threadIdx.x;
  int lane = tid & 63, w = tid >> 6;
  int kc = lane >> 4, ln = lane & 15;
  int pwave = pblk * 64 + w * 16;
  const short* arow = xoutb + ((size_t)(b * 8 + rl * rstep) * 2304 + pwave) * 128;

  f32x4 acc[8];
#pragma unroll
  for (int nf = 0; nf < 8; ++nf) acc[nf] = (f32x4){0.f, 0.f, 0.f, 0.f};
#pragma unroll
  for (int s = 0; s < 4; ++s) {
    bf16x8 a = *(const bf16x8*)(arow + ln * 128 + s * 32 + kc * 8);
#pragma unroll
    for (int nf = 0; nf < 8; ++nf) {
      bf16x8 bv = *(const bf16x8*)(w2b + (nf * 16 + ln) * 128 + s * 32 + kc * 8);
      acc[nf] = __builtin_amdgcn_mfma_f32_16x16x32_bf16(a, bv, acc[nf], 0, 0, 0);
    }
  }

  // heads: h = lrelu(acc + b2); attn += wa*h; z[j] += wz[j]*h
  float attn_acc[4] = {0.f, 0.f, 0.f, 0.f};
  float zacc[4][4];
#pragma unroll
  for (int j = 0; j < 4; ++j)
#pragma unroll
    for (int q = 0; q < 4; ++q) zacc[j][q] = 0.f;
#pragma unroll
  for (int nf = 0; nf < 8; ++nf) {
    int n = nf * 16 + ln;
    float bb2 = b2[n];
    float wan = wa[n];
    float wz0 = wz[n], wz1 = wz[128 + n], wz2 = wz[256 + n], wz3 = wz[384 + n];
#pragma unroll
    for (int q = 0; q < 4; ++q) {
      float h = lrelu_f(acc[nf][q] + bb2);
      attn_acc[q] = fmaf(wan, h, attn_acc[q]);
      zacc[0][q] = fmaf(wz0, h, zacc[0][q]);
      zacc[1][q] = fmaf(wz1, h, zacc[1][q]);
      zacc[2][q] = fmaf(wz2, h, zacc[2][q]);
      zacc[3][q] = fmaf(wz3, h, zacc[3][q]);
    }
  }
  // butterfly reduce over the 16 n-lanes (lane bits 0..3)
#pragma unroll
  for (int off = 1; off < 16; off <<= 1) {
#pragma unroll
    for (int q = 0; q < 4; ++q) {
      attn_acc[q] += __shfl_xor(attn_acc[q], off);
#pragma unroll
      for (int j = 0; j < 4; ++j) zacc[j][q] += __shfl_xor(zacc[j][q], off);
    }
  }
  if (ln == 0) {
    float ba0 = ba[0];
#pragma unroll
    for (int q = 0; q < 4; ++q) {
      int pix = pwave + kc * 4 + q;
      attn_out[((size_t)b * nR + rl) * 2304 + pix] = attn_acc[q] + ba0;
#pragma unroll
      for (int j = 0; j < 4; ++j)
        z_out[(((size_t)b * 4 + j) * nR + rl) * 2304 + pix] = zacc[j][q] + bz[j];
    }
  }
}

// ---------------- attn scatter + p_r; also p_r / offsets outputs ----------------
__global__ void k_attn_combine(const float* __restrict__ a0buf, const float* __restrict__ a1buf,
                               const float* __restrict__ scal, float* __restrict__ out0,
                               float* __restrict__ out2, float* __restrict__ out4) {
  int idx = blockIdx.x * blockDim.x + threadIdx.x;
  if (idx < 8) {
    float off = off_r(idx);
    out4[idx] = off;
    float q = off / (float)PI_D;
    out2[idx] = -0.5f * q * q - logf((float)PI_D) - 0.5f * logf(2.0f * (float)PI_D);
  }
  if (idx >= 147456) return;
  int pix = idx % 2304;
  int t = idx / 2304;
  int r = t & 7, b = t >> 3;
  float v = scal[3] * a1buf[idx];
  if (!(r & 1)) v += scal[2] * a0buf[((size_t)b * 4 + (r >> 1)) * 2304 + pix];
  float q = off_r(r) / (float)PI_D;
  v += -0.5f * q * q - logf((float)PI_D) - 0.5f * logf(2.0f * (float)PI_D);
  out0[idx] = v;
}

// ---------------- per-batch softmax / log_softmax over 18432 ----------------
__global__ __launch_bounds__(1024) void k_softmax(const float* __restrict__ out0,
                                                  const float* __restrict__ g,
                                                  float* __restrict__ out1,
                                                  float* __restrict__ out3) {
  int b = blockIdx.x;
  int tid = threadIdx.x;
  const float* v = out0 + (size_t)b * 18432;
  const float* gb = g + (size_t)b * 18432;
  float vl[18], gl[18];
  float m1 = -1e30f, m2 = -1e30f;
#pragma unroll
  for (int t = 0; t < 18; ++t) {
    float vv = v[tid + (t << 10)];
    float gg = gb[tid + (t << 10)];
    vl[t] = vv;
    gl[t] = vv + gg;
    m1 = fmaxf(m1, vv);
    m2 = fmaxf(m2, gl[t]);
  }
  __shared__ float red[32];
  for (int off = 32; off > 0; off >>= 1) {
    m1 = fmaxf(m1, __shfl_xor(m1, off));
    m2 = fmaxf(m2, __shfl_xor(m2, off));
  }
  int wid = tid >> 6, lane = tid & 63;
  if (lane == 0) { red[wid] = m1; red[wid + 16] = m2; }
  __syncthreads();
  float M1 = red[0], M2 = red[16];
#pragma unroll
  for (int w = 1; w < 16; ++w) { M1 = fmaxf(M1, red[w]); M2 = fmaxf(M2, red[w + 16]); }
  __syncthreads();
  float s1 = 0.f, s2 = 0.f;
#pragma unroll
  for (int t = 0; t < 18; ++t) { s1 += expf(vl[t] - M1); s2 += expf(gl[t] - M2); }
  for (int off = 32; off > 0; off >>= 1) {
    s1 += __shfl_xor(s1, off);
    s2 += __shfl_xor(s2, off);
  }
  if (lane == 0) { red[wid] = s1; red[wid + 16] = s2; }
  __syncthreads();
  float S1 = 0.f, S2 = 0.f;
#pragma unroll
  for (int w = 0; w < 16; ++w) { S1 += red[w]; S2 += red[w + 16]; }
  float lse = M1 + logf(S1);
  float inv2 = 1.0f / S2;
  float* o1 = out1 + (size_t)b * 18432;
  float* o3 = out3 + (size_t)b * 18432;
#pragma unroll
  for (int t = 0; t < 18; ++t) {
    o1[tid + (t << 10)] = vl[t] - lse;
    o3[tid + (t << 10)] = expf(gl[t] - M2) * inv2;
  }
}

// ---------------- z scatter + theta ----------------
__global__ void k_ztheta(const float* __restrict__ z0buf, const float* __restrict__ z1buf,
                         const float* __restrict__ scal, float* __restrict__ out5,
                         float* __restrict__ out6) {
  int idx = blockIdx.x * blockDim.x + threadIdx.x;
  if (idx >= 589824) return;
  int pix = idx % 2304;
  int t = idx / 2304;
  int r = t & 7;
  t >>= 3;
  int c = t & 3;
  int b = t >> 2;
  float v = scal[3] * z1buf[idx];
  if (!(r & 1)) v += scal[2] * z0buf[(((size_t)b * 4 + c) * 4 + (r >> 1)) * 2304 + pix];
  out6[idx] = v;
  if (c == 0)      out5[(((size_t)b * 2 + 0) * 8 + r) * 2304 + pix] = v + off_r(r);
  else if (c == 1) out5[(((size_t)b * 2 + 1) * 8 + r) * 2304 + pix] = v;
}

// ---------------- launcher ----------------
extern "C" void kernel_launch(void* const* d_in, const int* in_sizes, int n_in,
                              void* d_out, int out_size, void* d_ws, size_t ws_size,
                              hipStream_t stream) {
  const float* x   = (const float*)d_in[0];
  const float* ksz = (const float*)d_in[1];
  const float* rdw = (const float*)d_in[2];
  const float* w0  = (const float*)d_in[3];
  const float* b0  = (const float*)d_in[4];
  const float* w1  = (const float*)d_in[5];
  const float* b1  = (const float*)d_in[6];
  const float* w2  = (const float*)d_in[7];
  const float* b2  = (const float*)d_in[8];
  const float* wa  = (const float*)d_in[9];
  const float* ba  = (const float*)d_in[10];
  const float* wz  = (const float*)d_in[11];
  const float* bz  = (const float*)d_in[12];
  const float* gks = (const float*)d_in[13];
  const float* grd = (const float*)d_in[14];
  const float* gat = (const float*)d_in[15];
  float* out = (float*)d_out;
  float* ws  = (float*)d_ws;

  float* scal = ws + OFF_SCAL;
  float* w0T  = ws + OFF_W0T;
  float* w1T  = ws + OFF_W1T;
  short* w2b  = (short*)(ws + OFF_W2B);
  short* bfr  = (short*)(ws + OFF_BF);
  short* xoutb = (short*)(ws + OFF_XOUTB);
  float* a0b  = ws + OFF_A0;
  float* a1b  = ws + OFF_A1;
  float* z0b  = ws + OFF_Z0;
  float* z1b  = ws + OFF_Z1;

  float* out0 = out;
  float* out1 = out + 147456;
  float* out2 = out + 294912;
  float* out3 = out + 294920;
  float* out4 = out + 442376;
  float* out5 = out + 442384;
  float* out6 = out + 737296;

  k_scalars<<<1, 64, 0, stream>>>(ksz, gks, rdw, grd, scal);
  k_transpose<<<817, 256, 0, stream>>>(w0, w1, w2, w0T, w1T, w2b);
  k_bprep<<<880, 256, 0, stream>>>(w0T, w1T, bfr);
  k_conv_mfma<<<2304, 256, 0, stream>>>(x, bfr, b0, b1, scal, xoutb);
  // i = 0: r-dim 4 (stride 2)
  k_pw_mfma<<<8 * 4 * 36, 256, 0, stream>>>(xoutb, w2b, b2, wa, ba, wz, bz,
                                            4, 2, a0b, z0b);
  // i = 1: r-dim 8 (stride 1)
  k_pw_mfma<<<8 * 8 * 36, 256, 0, stream>>>(xoutb, w2b + 128 * 128, b2 + 128, wa + 128,
                                            ba + 1, wz + 4 * 128, bz + 4,
                                            8, 1, a1b, z1b);
  k_attn_combine<<<576, 256, 0, stream>>>(a0b, a1b, scal, out0, out2, out4);
  k_softmax<<<8, 1024, 0, stream>>>(out0, gat, out1, out3);
  k_ztheta<<<2304, 256, 0, stream>>>(z0b, z1b, scal, out5, out6);
}

// Round 5
// 313.995 us; speedup vs baseline: 3.3871x; 1.0643x over previous
//
#include <hip/hip_runtime.h>
#include <hip/hip_bf16.h>
#include <math.h>

#define PI_D 3.14159265358979323846

typedef __attribute__((ext_vector_type(8))) short bf16x8;
typedef __attribute__((ext_vector_type(4))) float f32x4;

// ---------------- workspace layout (float offsets) ----------------
#define OFF_SCAL   0u                 // 4 floats
#define OFF_W2B    4u                 // 2*128*128 bf16 = 16384 floats [i][o'][k]
#define OFF_BF     16388u             // Bfrag: 8r*55c*4kb*128o*8j bf16 = 901120 floats
#define OFF_XOUTB  917508u            // 8*8*2304*128 bf16 = 9437184 floats
#define OFF_A0     10354692u          // 8*4*2304
#define OFF_A1     10428420u          // 8*8*2304
#define OFF_Z0     10575876u          // 8*4*4*2304
#define OFF_Z1     10870788u          // 8*4*8*2304 -> ends 11460612 floats = 45.8 MB

#define NS33 42                       // K-steps for 33-kernel (rows padded to 40 taps)
#define NS17 13                       // K-steps for 17-kernel (rows padded to 24 taps)

__device__ __forceinline__ float off_r(int r) {
  int m = (r <= 4) ? r : r - 8;
  return (float)(PI_D / 4.0) * (float)m;
}
__device__ __forceinline__ float lrelu_f(float v) { return (v >= 0.f) ? v : 0.01f * v; }
__device__ __forceinline__ short f2bf(float f) {
  __bf16 h = (__bf16)f;
  return __builtin_bit_cast(short, h);
}

// ---------------- fused prep: scalars + w2 cast + rotation/B-frag ----------------
// grid 880 x 256. bprep gathers directly from w0/w1 (L2-resident).
__global__ void k_prep(const float* __restrict__ kw, const float* __restrict__ gk,
                       const float* __restrict__ rw, const float* __restrict__ gr,
                       const float* __restrict__ w0, const float* __restrict__ w1,
                       const float* __restrict__ w2, float* __restrict__ scal,
                       short* __restrict__ w2b, short* __restrict__ bfrag) {
  int t = blockIdx.x * blockDim.x + threadIdx.x;
  if (t == 0) {
    float a0 = (kw[0] + gk[0]) * 0.1f, a1 = (kw[1] + gk[1]) * 0.1f;
    float m = fmaxf(a0, a1);
    float e0 = expf(a0 - m), e1 = expf(a1 - m), inv = 1.f / (e0 + e1);
    scal[0] = e0 * inv; scal[1] = e1 * inv;
    float b0 = (rw[0] + gr[0]) * 0.1f, b1 = (rw[1] + gr[1]) * 0.1f;
    m = fmaxf(b0, b1);
    e0 = expf(b0 - m); e1 = expf(b1 - m); inv = 1.f / (e0 + e1);
    scal[2] = e0 * inv; scal[3] = e1 * inv;
  }
  if (t < 2 * 128 * 128) w2b[t] = f2bf(w2[t]);   // [i][o'][k], k contiguous
  // ---- B-fragment build (fused rotation) ----
  int o = t & 127;
  int q = t >> 7;
  int kb = q & 3; q >>= 2;
  int c = q % 55; int r = q / 55;
  float theta = (float)(PI_D / 4.0) * (float)r;
  float cth = cosf(theta), sth = sinf(theta);
  short out[8];
#pragma unroll
  for (int j = 0; j < 8; ++j) {
    float val = 0.f;
    int kk, k, dy, dx;
    const float* wsrc;
    if (c < NS33) { kk = 32 * c + 8 * kb + j; k = 33; dy = kk / 40; dx = kk - 40 * dy; wsrc = w1; }
    else          { kk = 32 * (c - NS33) + 8 * kb + j; k = 17; dy = kk / 24; dx = kk - 24 * dy; wsrc = w0; }
    if (dy < k && dx < k) {
      int kk2 = k * k;
      const float* wo = wsrc + o * kk2;
      float cy = (2.0f * (float)dy + 1.0f) / (float)k - 1.0f;
      float cx = (2.0f * (float)dx + 1.0f) / (float)k - 1.0f;
      float sx = cth * cx - sth * cy;
      float sy = sth * cx + cth * cy;
      float fx = ((sx + 1.0f) * (float)k - 1.0f) * 0.5f;
      float fy = ((sy + 1.0f) * (float)k - 1.0f) * 0.5f;
      float x0f = floorf(fx), y0f = floorf(fy);
      int x0 = (int)x0f, y0 = (int)y0f;
      float wx1 = fx - x0f, wy1 = fy - y0f;
      float acc = 0.f;
#define CORNER(Y, X, CW) { int yy = (Y), xx = (X); \
      if (yy >= 0 && yy < k && xx >= 0 && xx < k) acc += wo[yy * k + xx] * (CW); }
      CORNER(y0,     x0,     (1.f - wy1) * (1.f - wx1));
      CORNER(y0,     x0 + 1, (1.f - wy1) * wx1);
      CORNER(y0 + 1, x0,     wy1 * (1.f - wx1));
      CORNER(y0 + 1, x0 + 1, wy1 * wx1);
#undef CORNER
      val = acc;
    }
    out[j] = f2bf(val);
  }
  *(bf16x8*)(bfrag + (size_t)t * 8) =
      (bf16x8){out[0], out[1], out[2], out[3], out[4], out[5], out[6], out[7]};
}

// ---------------- MFMA implicit-GEMM conv ----------------
// Two tile copies (content shift 1) separated by TDW+PADW dwords where
// (TDW+PADW)*4 % 128 == 8: both copies 8B-aligned AND bank-phase-matched
// (lane bank ~= vv%32 regardless of copy) -> ~2-way max conflicts (free).
#define TDW 3080                      // 35 rows x 88 cols (f32 dwords)
#define PADW 26                       // (3080+26)*4 = 12424 = 97*128 + 8
__global__ __launch_bounds__(256, 4) void k_conv_mfma(
    const float* __restrict__ x, const short* __restrict__ bfrag,
    const float* __restrict__ b17, const float* __restrict__ b33,
    const float* __restrict__ scal, short* __restrict__ xoutb) {
  __shared__ __align__(16) float tile[TDW + PADW + TDW];
  float* tB = tile + (TDW + PADW);
  int blk = blockIdx.x;
  int pt = blk % 36; int t2 = blk / 36; int r = t2 & 7, b = t2 >> 3;
  int p0 = pt * 64;
  int ybase = p0 / 48;
  int tid = threadIdx.x;
  for (int idx = tid; idx < TDW; idx += 256) {
    int ty = idx / 88, tx = idx - ty * 88;
    int gy = ybase + ty - 8, gx = tx - 8;
    float v = 0.f;
    if (gy >= 0 && gy < 64 && gx >= 0 && gx < 64) v = x[(b * 64 + gy) * 64 + gx];
    tile[idx] = v;
    if (idx > 0) tB[idx - 1] = v;
  }
  for (int idx = tid; idx < PADW; idx += 256) tile[TDW + idx] = 0.f;  // pad + tB[TDW-1]
  if (tid == 0) tB[TDW - 1] = 0.f;
  __syncthreads();

  int lane = tid & 63, w = tid >> 6;
  int wm = w >> 1, wn = w & 1;
  int kc = lane >> 4;
  int ln = lane & 15;
  int mloc[2];
#pragma unroll
  for (int mf = 0; mf < 2; ++mf) {
    int p = p0 + wm * 32 + mf * 16 + ln;
    int ym = p / 48, xm = p - ym * 48;
    mloc[mf] = (ym - ybase) * 88 + xm;
  }
  const short* bb = bfrag + (size_t)r * (55 * 4 * 128 * 8);
  int nb0 = wn * 64;

  f32x4 acc33[2][4];
#pragma unroll
  for (int mf = 0; mf < 2; ++mf)
#pragma unroll
    for (int nf = 0; nf < 4; ++nf) acc33[mf][nf] = (f32x4){0.f, 0.f, 0.f, 0.f};

#define LOADB(dst, cg)                                                          \
  {                                                                             \
    _Pragma("unroll")                                                           \
    for (int nf = 0; nf < 4; ++nf)                                              \
      dst[nf] = *(const bf16x8*)(bb + ((size_t)((cg)*4 + kc) * 128 + nb0 + nf * 16 + ln) * 8); \
  }
#define READA(dst, vv)                                                          \
  {                                                                             \
    int s_ = (vv) & 1;                                                          \
    const float2* pp_ = (const float2*)(tile + s_ * (TDW + PADW) + ((vv) & ~1));\
    float2 f0_ = pp_[0], f1_ = pp_[1], f2_ = pp_[2], f3_ = pp_[3];              \
    dst = (bf16x8){f2bf(f0_.x), f2bf(f0_.y), f2bf(f1_.x), f2bf(f1_.y),          \
                   f2bf(f2_.x), f2bf(f2_.y), f2bf(f3_.x), f2bf(f3_.y)};         \
  }

  // ---- phase 1: 33x33 kernel ----
  {
    int dxb = 8 * kc;
    int off = dxb;
    bf16x8 bc[4], bn[4];
    LOADB(bc, 0);
    for (int c = 0; c < NS33; ++c) {
      if (c + 1 < NS33) LOADB(bn, c + 1);
      bf16x8 a0, a1;
      READA(a0, mloc[0] + off);
      READA(a1, mloc[1] + off);
#pragma unroll
      for (int nf = 0; nf < 4; ++nf) {
        acc33[0][nf] = __builtin_amdgcn_mfma_f32_16x16x32_bf16(a0, bc[nf], acc33[0][nf], 0, 0, 0);
        acc33[1][nf] = __builtin_amdgcn_mfma_f32_16x16x32_bf16(a1, bc[nf], acc33[1][nf], 0, 0, 0);
      }
#pragma unroll
      for (int nf = 0; nf < 4; ++nf) bc[nf] = bn[nf];
      int nd = dxb + 32;
      int wr = (nd >= 40);
      dxb = wr ? nd - 40 : nd;
      off += wr ? 80 : 32;
    }
  }

  // ---- phase 2: 17x17 kernel ----
  f32x4 acc17[2][4];
#pragma unroll
  for (int mf = 0; mf < 2; ++mf)
#pragma unroll
    for (int nf = 0; nf < 4; ++nf) acc17[mf][nf] = (f32x4){0.f, 0.f, 0.f, 0.f};
  {
    int t8 = 8 * kc;
    int dy0 = t8 / 24;
    int dxb = t8 - 24 * dy0;
    int off = (8 + dy0) * 88 + 8 + dxb;
    for (int c = 0; c < NS17; ++c) {
      bf16x8 bc[4];
      LOADB(bc, NS33 + c);
      bf16x8 a0, a1;
      READA(a0, mloc[0] + off);
      READA(a1, mloc[1] + off);
#pragma unroll
      for (int nf = 0; nf < 4; ++nf) {
        acc17[0][nf] = __builtin_amdgcn_mfma_f32_16x16x32_bf16(a0, bc[nf], acc17[0][nf], 0, 0, 0);
        acc17[1][nf] = __builtin_amdgcn_mfma_f32_16x16x32_bf16(a1, bc[nf], acc17[1][nf], 0, 0, 0);
      }
      int nd = dxb + 8;
      int wr = (nd >= 24);
      dxb = wr ? nd - 24 : nd;
      off += wr ? 160 : 96;
    }
  }
#undef LOADB
#undef READA

  // ---- epilogue: bias, lrelu, alpha-combine, bf16 store ----
  float a0s = scal[0], a1s = scal[1];
  int dq = lane >> 4;
#pragma unroll
  for (int nf = 0; nf < 4; ++nf) {
    int n = nb0 + nf * 16 + ln;
    float bb17 = b17[n], bb33 = b33[n];
#pragma unroll
    for (int mf = 0; mf < 2; ++mf) {
#pragma unroll
      for (int i = 0; i < 4; ++i) {
        int m = wm * 32 + mf * 16 + dq * 4 + i;
        float v = a0s * lrelu_f(acc17[mf][nf][i] + bb17)
                + a1s * lrelu_f(acc33[mf][nf][i] + bb33);
        xoutb[((size_t)(b * 8 + r) * 2304 + p0 + m) * 128 + n] = f2bf(v);
      }
    }
  }
}

// ---------------- MFMA 1x1 conv + fused heads (no LDS), both r-dims ----------------
// blocks [0,1152): i=0 (nR=4, rstep=2); [1152,3456): i=1 (nR=8, rstep=1)
__global__ __launch_bounds__(256, 8) void k_pw_mfma(
    const short* __restrict__ xoutb, const short* __restrict__ w2b_,
    const float* __restrict__ b2_, const float* __restrict__ wa_,
    const float* __restrict__ ba_, const float* __restrict__ wz_,
    const float* __restrict__ bz_,
    float* __restrict__ a0buf, float* __restrict__ z0buf,
    float* __restrict__ a1buf, float* __restrict__ z1buf) {
  int blk = blockIdx.x;
  int i1 = (blk >= 1152);
  int lblk = i1 ? blk - 1152 : blk;
  int nR = i1 ? 8 : 4, rstep = i1 ? 1 : 2;
  const short* w2b = w2b_ + (i1 ? 128 * 128 : 0);
  const float* b2 = b2_ + (i1 ? 128 : 0);
  const float* wa = wa_ + (i1 ? 128 : 0);
  const float* ba = ba_ + i1;
  const float* wz = wz_ + (i1 ? 512 : 0);
  const float* bz = bz_ + (i1 ? 4 : 0);
  float* attn_out = i1 ? a1buf : a0buf;
  float* z_out = i1 ? z1buf : z0buf;

  int pblk = lblk % 36;
  int t = lblk / 36;
  int rl = t % nR;
  int b = t / nR;
  int tid = threadIdx.x;
  int lane = tid & 63, w = tid >> 6;
  int kc = lane >> 4, ln = lane & 15;
  int pwave = pblk * 64 + w * 16;
  const short* arow = xoutb + ((size_t)(b * 8 + rl * rstep) * 2304 + pwave) * 128;

  f32x4 acc[8];
#pragma unroll
  for (int nf = 0; nf < 8; ++nf) acc[nf] = (f32x4){0.f, 0.f, 0.f, 0.f};
#pragma unroll
  for (int s = 0; s < 4; ++s) {
    bf16x8 a = *(const bf16x8*)(arow + ln * 128 + s * 32 + kc * 8);
#pragma unroll
    for (int nf = 0; nf < 8; ++nf) {
      bf16x8 bv = *(const bf16x8*)(w2b + (nf * 16 + ln) * 128 + s * 32 + kc * 8);
      acc[nf] = __builtin_amdgcn_mfma_f32_16x16x32_bf16(a, bv, acc[nf], 0, 0, 0);
    }
  }

  float attn_acc[4] = {0.f, 0.f, 0.f, 0.f};
  float zacc[4][4];
#pragma unroll
  for (int j = 0; j < 4; ++j)
#pragma unroll
    for (int q = 0; q < 4; ++q) zacc[j][q] = 0.f;
#pragma unroll
  for (int nf = 0; nf < 8; ++nf) {
    int n = nf * 16 + ln;
    float bb2 = b2[n];
    float wan = wa[n];
    float wz0 = wz[n], wz1 = wz[128 + n], wz2 = wz[256 + n], wz3 = wz[384 + n];
#pragma unroll
    for (int q = 0; q < 4; ++q) {
      float h = lrelu_f(acc[nf][q] + bb2);
      attn_acc[q] = fmaf(wan, h, attn_acc[q]);
      zacc[0][q] = fmaf(wz0, h, zacc[0][q]);
      zacc[1][q] = fmaf(wz1, h, zacc[1][q]);
      zacc[2][q] = fmaf(wz2, h, zacc[2][q]);
      zacc[3][q] = fmaf(wz3, h, zacc[3][q]);
    }
  }
#pragma unroll
  for (int off = 1; off < 16; off <<= 1) {
#pragma unroll
    for (int q = 0; q < 4; ++q) {
      attn_acc[q] += __shfl_xor(attn_acc[q], off);
#pragma unroll
      for (int j = 0; j < 4; ++j) zacc[j][q] += __shfl_xor(zacc[j][q], off);
    }
  }
  if (ln == 0) {
    float ba0 = ba[0];
#pragma unroll
    for (int q = 0; q < 4; ++q) {
      int pix = pwave + kc * 4 + q;
      attn_out[((size_t)b * nR + rl) * 2304 + pix] = attn_acc[q] + ba0;
#pragma unroll
      for (int j = 0; j < 4; ++j)
        z_out[(((size_t)b * 4 + j) * nR + rl) * 2304 + pix] = zacc[j][q] + bz[j];
    }
  }
}

// ---------------- attn scatter + p_r; also p_r / offsets outputs ----------------
__global__ void k_attn_combine(const float* __restrict__ a0buf, const float* __restrict__ a1buf,
                               const float* __restrict__ scal, float* __restrict__ out0,
                               float* __restrict__ out2, float* __restrict__ out4) {
  int idx = blockIdx.x * blockDim.x + threadIdx.x;
  if (idx < 8) {
    float off = off_r(idx);
    out4[idx] = off;
    float q = off / (float)PI_D;
    out2[idx] = -0.5f * q * q - logf((float)PI_D) - 0.5f * logf(2.0f * (float)PI_D);
  }
  if (idx >= 147456) return;
  int pix = idx % 2304;
  int t = idx / 2304;
  int r = t & 7, b = t >> 3;
  float v = scal[3] * a1buf[idx];
  if (!(r & 1)) v += scal[2] * a0buf[((size_t)b * 4 + (r >> 1)) * 2304 + pix];
  float q = off_r(r) / (float)PI_D;
  v += -0.5f * q * q - logf((float)PI_D) - 0.5f * logf(2.0f * (float)PI_D);
  out0[idx] = v;
}

// ---------------- per-batch softmax / log_softmax over 18432 ----------------
__global__ __launch_bounds__(1024) void k_softmax(const float* __restrict__ out0,
                                                  const float* __restrict__ g,
                                                  float* __restrict__ out1,
                                                  float* __restrict__ out3) {
  int b = blockIdx.x;
  int tid = threadIdx.x;
  const float* v = out0 + (size_t)b * 18432;
  const float* gb = g + (size_t)b * 18432;
  float vl[18], gl[18];
  float m1 = -1e30f, m2 = -1e30f;
#pragma unroll
  for (int t = 0; t < 18; ++t) {
    float vv = v[tid + (t << 10)];
    float gg = gb[tid + (t << 10)];
    vl[t] = vv;
    gl[t] = vv + gg;
    m1 = fmaxf(m1, vv);
    m2 = fmaxf(m2, gl[t]);
  }
  __shared__ float red[32];
  for (int off = 32; off > 0; off >>= 1) {
    m1 = fmaxf(m1, __shfl_xor(m1, off));
    m2 = fmaxf(m2, __shfl_xor(m2, off));
  }
  int wid = tid >> 6, lane = tid & 63;
  if (lane == 0) { red[wid] = m1; red[wid + 16] = m2; }
  __syncthreads();
  float M1 = red[0], M2 = red[16];
#pragma unroll
  for (int w = 1; w < 16; ++w) { M1 = fmaxf(M1, red[w]); M2 = fmaxf(M2, red[w + 16]); }
  __syncthreads();
  float s1 = 0.f, s2 = 0.f;
#pragma unroll
  for (int t = 0; t < 18; ++t) { s1 += expf(vl[t] - M1); s2 += expf(gl[t] - M2); }
  for (int off = 32; off > 0; off >>= 1) {
    s1 += __shfl_xor(s1, off);
    s2 += __shfl_xor(s2, off);
  }
  if (lane == 0) { red[wid] = s1; red[wid + 16] = s2; }
  __syncthreads();
  float S1 = 0.f, S2 = 0.f;
#pragma unroll
  for (int w = 0; w < 16; ++w) { S1 += red[w]; S2 += red[w + 16]; }
  float lse = M1 + logf(S1);
  float inv2 = 1.0f / S2;
  float* o1 = out1 + (size_t)b * 18432;
  float* o3 = out3 + (size_t)b * 18432;
#pragma unroll
  for (int t = 0; t < 18; ++t) {
    o1[tid + (t << 10)] = vl[t] - lse;
    o3[tid + (t << 10)] = expf(gl[t] - M2) * inv2;
  }
}

// ---------------- z scatter + theta ----------------
__global__ void k_ztheta(const float* __restrict__ z0buf, const float* __restrict__ z1buf,
                         const float* __restrict__ scal, float* __restrict__ out5,
                         float* __restrict__ out6) {
  int idx = blockIdx.x * blockDim.x + threadIdx.x;
  if (idx >= 589824) return;
  int pix = idx % 2304;
  int t = idx / 2304;
  int r = t & 7;
  t >>= 3;
  int c = t & 3;
  int b = t >> 2;
  float v = scal[3] * z1buf[idx];
  if (!(r & 1)) v += scal[2] * z0buf[(((size_t)b * 4 + c) * 4 + (r >> 1)) * 2304 + pix];
  out6[idx] = v;
  if (c == 0)      out5[(((size_t)b * 2 + 0) * 8 + r) * 2304 + pix] = v + off_r(r);
  else if (c == 1) out5[(((size_t)b * 2 + 1) * 8 + r) * 2304 + pix] = v;
}

// ---------------- launcher ----------------
extern "C" void kernel_launch(void* const* d_in, const int* in_sizes, int n_in,
                              void* d_out, int out_size, void* d_ws, size_t ws_size,
                              hipStream_t stream) {
  const float* x   = (const float*)d_in[0];
  const float* ksz = (const float*)d_in[1];
  const float* rdw = (const float*)d_in[2];
  const float* w0  = (const float*)d_in[3];
  const float* b0  = (const float*)d_in[4];
  const float* w1  = (const float*)d_in[5];
  const float* b1  = (const float*)d_in[6];
  const float* w2  = (const float*)d_in[7];
  const float* b2  = (const float*)d_in[8];
  const float* wa  = (const float*)d_in[9];
  const float* ba  = (const float*)d_in[10];
  const float* wz  = (const float*)d_in[11];
  const float* bz  = (const float*)d_in[12];
  const float* gks = (const float*)d_in[13];
  const float* grd = (const float*)d_in[14];
  const float* gat = (const float*)d_in[15];
  float* out = (float*)d_out;
  float* ws  = (float*)d_ws;

  float* scal = ws + OFF_SCAL;
  short* w2b  = (short*)(ws + OFF_W2B);
  short* bfr  = (short*)(ws + OFF_BF);
  short* xoutb = (short*)(ws + OFF_XOUTB);
  float* a0b  = ws + OFF_A0;
  float* a1b  = ws + OFF_A1;
  float* z0b  = ws + OFF_Z0;
  float* z1b  = ws + OFF_Z1;

  float* out0 = out;
  float* out1 = out + 147456;
  float* out2 = out + 294912;
  float* out3 = out + 294920;
  float* out4 = out + 442376;
  float* out5 = out + 442384;
  float* out6 = out + 737296;

  k_prep<<<880, 256, 0, stream>>>(ksz, gks, rdw, grd, w0, w1, w2, scal, w2b, bfr);
  k_conv_mfma<<<2304, 256, 0, stream>>>(x, bfr, b0, b1, scal, xoutb);
  k_pw_mfma<<<3456, 256, 0, stream>>>(xoutb, w2b, b2, wa, ba, wz, bz,
                                      a0b, z0b, a1b, z1b);
  k_attn_combine<<<576, 256, 0, stream>>>(a0b, a1b, scal, out0, out2, out4);
  k_softmax<<<8, 1024, 0, stream>>>(out0, gat, out1, out3);
  k_ztheta<<<2304, 256, 0, stream>>>(z0b, z1b, scal, out5, out6);
}